// Round 10
// baseline (169.804 us; speedup 1.0000x reference)
//
#include <hip/hip_runtime.h>

// SDF volume rendering (NeuS/VolSDF-style), float32 in/out.
//
// Per ray (96 samples):
//   alpha_i = 1 - exp(-beta * sigmoid(-sdf_i * beta))
//   t_i     = 1 - alpha_i + 1e-10
//   trans_i = exclusive cumprod of t ;  w_i = alpha_i * trans_i
//   depth   = sum w_i * z_i ;  rgb_c = sum w_i * rgb_{i,c}
//
// R14: R13 falsified the load-serialization theory (loads provably parallel,
// still 2.8 TB/s read). New model: L2 line-REQUEST rate, not bytes. Each of
// the 3 rgb loads is a stride-36B lane scatter spanning the same 2304-B
// range -> 3 instructions x ~36 lines = 108 line requests for 36 unique
// lines (no cross-instruction dedup). Total 132 requests/wave; measured
// 32768 waves x 132 / 44.8us = 96.6 G lines/s == the 98 G lines/s fabric
// ceiling (6.3 TB/s / 64B). The kernel was at the REQUEST roofline all
// session -- invariant to scheduling, MLP, occupancy.
//
// Fix: rgb loaded lane-contiguously as float4 (each line touched once),
// redistributed through LDS (9216 B/block, odd stride-9 reads = conflict-
// free), sdf/z stay direct (already single-touch). Passthrough stays in
// the separate copy dispatch (R12-proven ~13us at ~7.7 TB/s).

#define SDFR_NS 96
#define SDFR_RPB 8      // rays per compute block (256 thr, 32 lanes/ray)

struct f3 { float x, y, z; };                              // 12B -> dwordx3
typedef float fv4 __attribute__((ext_vector_type(4)));     // true vector type

// ---------------------------------------------------------------- compute --
__global__ __launch_bounds__(256, 8) void sdf_compute_kernel(
    const float* __restrict__ rgb,      // [N*96*3]
    const float* __restrict__ sdf,      // [N*96]
    const float* __restrict__ z_vals,   // [N*96]
    const int*   __restrict__ beta_p,
    float* __restrict__ out_depth,      // [N]
    float* __restrict__ out_rgb,        // [N,3]
    int n_rays)
{
    __shared__ __align__(16) float rgbs[SDFR_RPB * SDFR_NS * 3]; // 9216 B

    const int t        = threadIdx.x;
    const int g        = t >> 5;         // ray within block, 0..7
    const int l        = t & 31;         // lane l owns samples [3l, 3l+3)
    const int base_ray = blockIdx.x * SDFR_RPB;
    const int ray      = base_ray + g;

    const fv4* __restrict__ rgb4 = (const fv4*)rgb;
    fv4* rs4 = (fv4*)rgbs;
    const int bb = blockIdx.x * (SDFR_RPB * SDFR_NS * 3 / 4);  // 576 f4/block

    const bool full = (base_ray + SDFR_RPB <= n_rays);
    f3 sv = {0.f, 0.f, 0.f}, zv = {0.f, 0.f, 0.f};

    if (full) {
        // sdf/z: direct dwordx3 (lane-contiguous, single-touch pattern)
        const int sb = ray * SDFR_NS + 3 * l;
        sv = *(const f3*)(sdf    + sb);
        zv = *(const f3*)(z_vals + sb);

        // rgb: lane-contiguous float4 stage (each 64-B line touched ONCE)
        fv4 v0 = rgb4[bb + t];
        fv4 v1 = rgb4[bb + 256 + t];
        fv4 v2 = {0.f, 0.f, 0.f, 0.f};
        const bool h = (t < 64);             // wave-uniform (wave 0 only)
        if (h) v2 = rgb4[bb + 512 + t];
        __builtin_amdgcn_sched_barrier(0);   // all global loads issued first

        rs4[t]       = v0;
        rs4[256 + t] = v1;
        if (h) rs4[512 + t] = v2;
    } else {
        // tail path (never taken at N=65536): guarded
        if (ray < n_rays) {
            const int sb = ray * SDFR_NS + 3 * l;
            sv = *(const f3*)(sdf    + sb);
            zv = *(const f3*)(z_vals + sb);
        }
        const int lim = n_rays * (SDFR_NS * 3 / 4);
        for (int k = t; k < SDFR_RPB * SDFR_NS * 3 / 4; k += 256)
            if (bb + k < lim) rs4[k] = rgb4[bb + k];
    }

    __syncthreads();
    if (ray >= n_rays) return;

    // LDS redistribute: 9 floats at float-stride 9 (odd -> conflict-free)
    const float* rf = rgbs + g * (SDFR_NS * 3) + 9 * l;
    const float c0 = rf[0], c1 = rf[1], c2 = rf[2];
    const float c3 = rf[3], c4 = rf[4], c5 = rf[5];
    const float c6 = rf[6], c7 = rf[7], c8 = rf[8];

    // beta decode: small int is the value; huge magnitude is an f32 pattern
    int bi = *beta_p;
    float beta;
    if (bi > 1000000 || bi < -1000000) {
        union { int i; float f; } u; u.i = bi; beta = u.f;
    } else {
        beta = (float)bi;
    }

    // sigmoid(-s*beta) = 1/(1+exp(s*beta)); e = exp(-beta*sig)
    const float e0 = __expf(-beta * __builtin_amdgcn_rcpf(1.0f + __expf(sv.x * beta)));
    const float e1 = __expf(-beta * __builtin_amdgcn_rcpf(1.0f + __expf(sv.y * beta)));
    const float e2 = __expf(-beta * __builtin_amdgcn_rcpf(1.0f + __expf(sv.z * beta)));
    const float a0 = 1.0f - e0, t0 = e0 + 1e-10f;
    const float a1 = 1.0f - e1, t1 = e1 + 1e-10f;
    const float a2 = 1.0f - e2, t2 = e2 + 1e-10f;

    // 32-lane exclusive prefix product of per-lane local product
    float scan = t0 * t1 * t2;
    #pragma unroll
    for (int d = 1; d < 32; d <<= 1) {
        float v = __shfl_up(scan, d, 32);
        if (l >= d) scan *= v;
    }
    float E = __shfl_up(scan, 1, 32);
    if (l == 0) E = 1.0f;

    const float w0 = a0 * E;
    const float w1 = a1 * E * t0;
    const float w2 = a2 * E * t0 * t1;

    float depth = w0 * zv.x + w1 * zv.y + w2 * zv.z;
    float r0    = w0 * c0 + w1 * c3 + w2 * c6;
    float r1    = w0 * c1 + w1 * c4 + w2 * c7;
    float r2    = w0 * c2 + w1 * c5 + w2 * c8;

    #pragma unroll
    for (int d = 16; d >= 1; d >>= 1) {
        depth += __shfl_xor(depth, d, 32);
        r0    += __shfl_xor(r0, d, 32);
        r1    += __shfl_xor(r1, d, 32);
        r2    += __shfl_xor(r2, d, 32);
    }

    // only stores: 16B per ray, at wave end
    if (l == 0) {
        out_depth[ray] = depth;
        f3 o; o.x = r0; o.y = r1; o.z = r2;
        *(f3*)(out_rgb + ray * 3) = o;
    }
}

// ------------------------------------------------------------------- copy --
#define SDFR_CPB 2048   // copy grid: 2048 blocks x 256 thr (ubench shape)

__global__ __launch_bounds__(256, 8) void sdf_copy_kernel(
    const float* __restrict__ sdf,
    const float* __restrict__ z_vals,
    float* __restrict__ out_sdf,
    float* __restrict__ out_z,
    int n_rays)
{
    const int n4     = (n_rays * SDFR_NS) / 4;   // 1,572,864 @ N=65536
    const int stride = SDFR_CPB * 256;           // 524,288 -> 3 iters
    const fv4* __restrict__ s4 = (const fv4*)sdf;
    const fv4* __restrict__ z4 = (const fv4*)z_vals;
    fv4* __restrict__ os4 = (fv4*)out_sdf;
    fv4* __restrict__ oz4 = (fv4*)out_z;

    for (int i = blockIdx.x * 256 + threadIdx.x; i < n4; i += stride) {
        const fv4 a = s4[i];
        const fv4 b = z4[i];
        __builtin_nontemporal_store(a, os4 + i);
        __builtin_nontemporal_store(b, oz4 + i);
    }
}

extern "C" void kernel_launch(void* const* d_in, const int* in_sizes, int n_in,
                              void* d_out, int out_size, void* d_ws, size_t ws_size,
                              hipStream_t stream) {
    (void)n_in; (void)d_ws; (void)ws_size; (void)out_size;

    const float* rgb    = (const float*)d_in[0];
    const float* sdf    = (const float*)d_in[1];
    const float* z      = (const float*)d_in[2];
    const int*   beta_p = (const int*)d_in[3];

    const int n_rays = in_sizes[1] / SDFR_NS;  // 65536

    // output layout (f32): depth[N] | rgb[N*3] | sdf[N*96] | z[N*96]
    float* out_depth = (float*)d_out;
    float* out_rgb   = out_depth + n_rays;
    float* out_sdf   = out_rgb   + (size_t)n_rays * 3;
    float* out_z     = out_sdf   + (size_t)n_rays * SDFR_NS;

    // K1 first: its sdf/z reads leave them L3-hot for K2's copy.
    const int comp_blocks = (n_rays + SDFR_RPB - 1) / SDFR_RPB;   // 8192
    sdf_compute_kernel<<<comp_blocks, 256, 0, stream>>>(
        rgb, sdf, z, beta_p, out_depth, out_rgb, n_rays);

    sdf_copy_kernel<<<SDFR_CPB, 256, 0, stream>>>(
        sdf, z, out_sdf, out_z, n_rays);
}

// Round 11
// 166.067 us; speedup vs baseline: 1.0225x; 1.0225x over previous
//
#include <hip/hip_runtime.h>

// SDF volume rendering (NeuS/VolSDF-style), float32 in/out.
//
// Per ray (96 samples):
//   alpha_i = 1 - exp(-beta * sigmoid(-sdf_i * beta))
//   t_i     = 1 - alpha_i + 1e-10
//   trans_i = exclusive cumprod of t ;  w_i = alpha_i * trans_i
//   depth   = sum w_i * z_i ;  rgb_c = sum w_i * rgb_{i,c}
//
// R15: session ledger -- load width X, LDS staging X, MLP X (R13 keep-alive),
// store drain X (R12 split), pipelining X (R6/R10), line-request rate X
// (R14). Compute reads 126 MB in 46us = 2.7 TB/s with NO pipe >20% busy,
// while fillBuffer streams 6.7 TB/s in the same run. FETCH=61.4 MB < 126:
// ~half the reads (incl. part of rgb) are served from Infinity Cache. All
// our fast reference numbers are HBM-path; L3-READ has no measured ceiling
// in the docs. Hypothesis: L3 read path for 64B-line fills is capped
// ~1.5-2 TB/s -> 50/50 L3/HBM mix == the observed 2.7 TB/s, invariant to
// every scheduling knob (exactly the session's signature).
//
// Probe: __builtin_nontemporal_load on the rgb staging loads ONLY (16B-
// aligned fv4; nt = no-allocate, HBM-direct). sdf/z stay cached (the copy
// dispatch re-reads them). One variable vs R14. Validity check: compute
// FETCH_SIZE must jump 61 -> ~95-115 MB, else the nt bit didn't take.

#define SDFR_NS 96
#define SDFR_RPB 8      // rays per compute block (256 thr, 32 lanes/ray)

struct f3 { float x, y, z; };                              // 12B -> dwordx3
typedef float fv4 __attribute__((ext_vector_type(4)));     // true vector type

// ---------------------------------------------------------------- compute --
__global__ __launch_bounds__(256, 8) void sdf_compute_kernel(
    const float* __restrict__ rgb,      // [N*96*3]
    const float* __restrict__ sdf,      // [N*96]
    const float* __restrict__ z_vals,   // [N*96]
    const int*   __restrict__ beta_p,
    float* __restrict__ out_depth,      // [N]
    float* __restrict__ out_rgb,        // [N,3]
    int n_rays)
{
    __shared__ __align__(16) float rgbs[SDFR_RPB * SDFR_NS * 3]; // 9216 B

    const int t        = threadIdx.x;
    const int g        = t >> 5;         // ray within block, 0..7
    const int l        = t & 31;         // lane l owns samples [3l, 3l+3)
    const int base_ray = blockIdx.x * SDFR_RPB;
    const int ray      = base_ray + g;

    const fv4* __restrict__ rgb4 = (const fv4*)rgb;
    fv4* rs4 = (fv4*)rgbs;
    const int bb = blockIdx.x * (SDFR_RPB * SDFR_NS * 3 / 4);  // 576 f4/block

    const bool full = (base_ray + SDFR_RPB <= n_rays);
    f3 sv = {0.f, 0.f, 0.f}, zv = {0.f, 0.f, 0.f};

    if (full) {
        // sdf/z: direct dwordx3 (lane-contiguous), CACHED (copy re-reads)
        const int sb = ray * SDFR_NS + 3 * l;
        sv = *(const f3*)(sdf    + sb);
        zv = *(const f3*)(z_vals + sb);

        // rgb: lane-contiguous float4 stage, NONTEMPORAL (zero reuse;
        // no-allocate -> HBM-direct path, bypasses the L3 read ceiling)
        fv4 v0 = __builtin_nontemporal_load(rgb4 + bb + t);
        fv4 v1 = __builtin_nontemporal_load(rgb4 + bb + 256 + t);
        fv4 v2 = {0.f, 0.f, 0.f, 0.f};
        const bool h = (t < 64);             // wave-uniform (wave 0 only)
        if (h) v2 = __builtin_nontemporal_load(rgb4 + bb + 512 + t);
        __builtin_amdgcn_sched_barrier(0);   // all global loads issued first

        rs4[t]       = v0;
        rs4[256 + t] = v1;
        if (h) rs4[512 + t] = v2;
    } else {
        // tail path (never taken at N=65536): guarded
        if (ray < n_rays) {
            const int sb = ray * SDFR_NS + 3 * l;
            sv = *(const f3*)(sdf    + sb);
            zv = *(const f3*)(z_vals + sb);
        }
        const int lim = n_rays * (SDFR_NS * 3 / 4);
        for (int k = t; k < SDFR_RPB * SDFR_NS * 3 / 4; k += 256)
            if (bb + k < lim) rs4[k] = rgb4[bb + k];
    }

    __syncthreads();
    if (ray >= n_rays) return;

    // LDS redistribute: 9 floats at float-stride 9 (odd -> conflict-free)
    const float* rf = rgbs + g * (SDFR_NS * 3) + 9 * l;
    const float c0 = rf[0], c1 = rf[1], c2 = rf[2];
    const float c3 = rf[3], c4 = rf[4], c5 = rf[5];
    const float c6 = rf[6], c7 = rf[7], c8 = rf[8];

    // beta decode: small int is the value; huge magnitude is an f32 pattern
    int bi = *beta_p;
    float beta;
    if (bi > 1000000 || bi < -1000000) {
        union { int i; float f; } u; u.i = bi; beta = u.f;
    } else {
        beta = (float)bi;
    }

    // sigmoid(-s*beta) = 1/(1+exp(s*beta)); e = exp(-beta*sig)
    const float e0 = __expf(-beta * __builtin_amdgcn_rcpf(1.0f + __expf(sv.x * beta)));
    const float e1 = __expf(-beta * __builtin_amdgcn_rcpf(1.0f + __expf(sv.y * beta)));
    const float e2 = __expf(-beta * __builtin_amdgcn_rcpf(1.0f + __expf(sv.z * beta)));
    const float a0 = 1.0f - e0, t0 = e0 + 1e-10f;
    const float a1 = 1.0f - e1, t1 = e1 + 1e-10f;
    const float a2 = 1.0f - e2, t2 = e2 + 1e-10f;

    // 32-lane exclusive prefix product of per-lane local product
    float scan = t0 * t1 * t2;
    #pragma unroll
    for (int d = 1; d < 32; d <<= 1) {
        float v = __shfl_up(scan, d, 32);
        if (l >= d) scan *= v;
    }
    float E = __shfl_up(scan, 1, 32);
    if (l == 0) E = 1.0f;

    const float w0 = a0 * E;
    const float w1 = a1 * E * t0;
    const float w2 = a2 * E * t0 * t1;

    float depth = w0 * zv.x + w1 * zv.y + w2 * zv.z;
    float r0    = w0 * c0 + w1 * c3 + w2 * c6;
    float r1    = w0 * c1 + w1 * c4 + w2 * c7;
    float r2    = w0 * c2 + w1 * c5 + w2 * c8;

    #pragma unroll
    for (int d = 16; d >= 1; d >>= 1) {
        depth += __shfl_xor(depth, d, 32);
        r0    += __shfl_xor(r0, d, 32);
        r1    += __shfl_xor(r1, d, 32);
        r2    += __shfl_xor(r2, d, 32);
    }

    // only stores: 16B per ray, at wave end
    if (l == 0) {
        out_depth[ray] = depth;
        f3 o; o.x = r0; o.y = r1; o.z = r2;
        *(f3*)(out_rgb + ray * 3) = o;
    }
}

// ------------------------------------------------------------------- copy --
#define SDFR_CPB 2048   // copy grid: 2048 blocks x 256 thr (ubench shape)

__global__ __launch_bounds__(256, 8) void sdf_copy_kernel(
    const float* __restrict__ sdf,
    const float* __restrict__ z_vals,
    float* __restrict__ out_sdf,
    float* __restrict__ out_z,
    int n_rays)
{
    const int n4     = (n_rays * SDFR_NS) / 4;   // 1,572,864 @ N=65536
    const int stride = SDFR_CPB * 256;           // 524,288 -> 3 iters
    const fv4* __restrict__ s4 = (const fv4*)sdf;
    const fv4* __restrict__ z4 = (const fv4*)z_vals;
    fv4* __restrict__ os4 = (fv4*)out_sdf;
    fv4* __restrict__ oz4 = (fv4*)out_z;

    for (int i = blockIdx.x * 256 + threadIdx.x; i < n4; i += stride) {
        const fv4 a = s4[i];
        const fv4 b = z4[i];
        __builtin_nontemporal_store(a, os4 + i);
        __builtin_nontemporal_store(b, oz4 + i);
    }
}

extern "C" void kernel_launch(void* const* d_in, const int* in_sizes, int n_in,
                              void* d_out, int out_size, void* d_ws, size_t ws_size,
                              hipStream_t stream) {
    (void)n_in; (void)d_ws; (void)ws_size; (void)out_size;

    const float* rgb    = (const float*)d_in[0];
    const float* sdf    = (const float*)d_in[1];
    const float* z      = (const float*)d_in[2];
    const int*   beta_p = (const int*)d_in[3];

    const int n_rays = in_sizes[1] / SDFR_NS;  // 65536

    // output layout (f32): depth[N] | rgb[N*3] | sdf[N*96] | z[N*96]
    float* out_depth = (float*)d_out;
    float* out_rgb   = out_depth + n_rays;
    float* out_sdf   = out_rgb   + (size_t)n_rays * 3;
    float* out_z     = out_sdf   + (size_t)n_rays * SDFR_NS;

    // K1 first: its sdf/z reads leave them L3-hot for K2's copy.
    const int comp_blocks = (n_rays + SDFR_RPB - 1) / SDFR_RPB;   // 8192
    sdf_compute_kernel<<<comp_blocks, 256, 0, stream>>>(
        rgb, sdf, z, beta_p, out_depth, out_rgb, n_rays);

    sdf_copy_kernel<<<SDFR_CPB, 256, 0, stream>>>(
        sdf, z, out_sdf, out_z, n_rays);
}